// Round 1
// baseline (507.794 us; speedup 1.0000x reference)
//
#include <hip/hip_runtime.h>

#define NN 50000
#define NE 800000
#define FIN 128
#define FH 64
#define FOUT 64
#define KC 1024

// ---------------------------------------------------------------------------
// Edge pass: in-degree histogram + pooled adjacency (stored TRANSPOSED:
// A_T[cv][cu] = A[cu][cv], so later column-ops over A become row-ops).
// ---------------------------------------------------------------------------
__global__ __launch_bounds__(256) void k_edge(const int* __restrict__ src,
                                              const int* __restrict__ dst,
                                              const int* __restrict__ cid,
                                              int* __restrict__ deg,
                                              float* __restrict__ AT) {
    int e = blockIdx.x * 256 + threadIdx.x;
    if (e >= NE) return;
    int s = src[e], d = dst[e];
    atomicAdd(&deg[d], 1);
    int cu = cid[s], cv = cid[d];
    if (cu != cv) AT[cv * KC + cu] = 1.0f;  // racing same-value stores: benign
}

// deg_p[t] = 1 + sum_s A[s][t] = 1 + rowsum(A_T[t]); dinv_p = rsqrt
__global__ __launch_bounds__(64) void k_degp(const float* __restrict__ AT,
                                             float* __restrict__ dinvp) {
    int t = blockIdx.x, lane = threadIdx.x;
    const float* row = AT + (size_t)t * KC;
    float s = 0.f;
    for (int i = lane; i < KC; i += 64) s += row[i];
    for (int o = 32; o; o >>= 1) s += __shfl_down(s, o);
    if (lane == 0) dinvp[t] = rsqrtf(1.0f + s);
}

// per-node: dinv = rsqrt(deg+1); cluster counts
__global__ __launch_bounds__(256) void k_node(const int* __restrict__ deg,
                                              const int* __restrict__ cid,
                                              float* __restrict__ dinv,
                                              int* __restrict__ counts) {
    int i = blockIdx.x * 256 + threadIdx.x;
    if (i >= NN) return;
    dinv[i] = rsqrtf((float)deg[i] + 1.0f);
    atomicAdd(&counts[cid[i]], 1);
}

// h = x @ W1.  Block = 256 thr = 4 row-quads x 64 cols; 16 rows/block,
// 4 rows/thread so each LDS W1 read feeds 4 FMAs.
__global__ __launch_bounds__(256) void k_gemm1(const float* __restrict__ x,
                                               const float* __restrict__ W1,
                                               float* __restrict__ h) {
    __shared__ float W1s[FIN * FH];  // 32 KB
    int t = threadIdx.x;
    {
        const float4* wv = (const float4*)W1;
        float4* sv = (float4*)W1s;
        for (int i = t; i < FIN * FH / 4; i += 256) sv[i] = wv[i];
    }
    __syncthreads();
    int col = t & 63, rq = t >> 6;
    int row0 = blockIdx.x * 16 + rq * 4;
    float acc0 = 0.f, acc1 = 0.f, acc2 = 0.f, acc3 = 0.f;
    const float4* x4 = (const float4*)x;
    const int L = FIN / 4;
    for (int k4 = 0; k4 < L; ++k4) {
        float4 a0 = x4[(size_t)(row0 + 0) * L + k4];
        float4 a1 = x4[(size_t)(row0 + 1) * L + k4];
        float4 a2 = x4[(size_t)(row0 + 2) * L + k4];
        float4 a3 = x4[(size_t)(row0 + 3) * L + k4];
        const float* wp = &W1s[k4 * 4 * FH + col];
        float w0 = wp[0], w1 = wp[FH], w2 = wp[2 * FH], w3 = wp[3 * FH];
        acc0 = fmaf(a0.x, w0, fmaf(a0.y, w1, fmaf(a0.z, w2, fmaf(a0.w, w3, acc0))));
        acc1 = fmaf(a1.x, w0, fmaf(a1.y, w1, fmaf(a1.z, w2, fmaf(a1.w, w3, acc1))));
        acc2 = fmaf(a2.x, w0, fmaf(a2.y, w1, fmaf(a2.z, w2, fmaf(a2.w, w3, acc2))));
        acc3 = fmaf(a3.x, w0, fmaf(a3.y, w1, fmaf(a3.z, w2, fmaf(a3.w, w3, acc3))));
    }
    h[(size_t)(row0 + 0) * FH + col] = acc0;
    h[(size_t)(row0 + 1) * FH + col] = acc1;
    h[(size_t)(row0 + 2) * FH + col] = acc2;
    h[(size_t)(row0 + 3) * FH + col] = acc3;
}

// edge scatter: agg[d] += h[s] * dinv[s]*dinv[d].  One wave-quad (64 lanes)
// per edge, grid-stride.
__global__ __launch_bounds__(256) void k_scatter(const int* __restrict__ src,
                                                 const int* __restrict__ dst,
                                                 const float* __restrict__ dinv,
                                                 const float* __restrict__ h,
                                                 float* __restrict__ agg) {
    int lane = threadIdx.x & 63;
    int quad0 = blockIdx.x * 4 + (threadIdx.x >> 6);
    int stride = gridDim.x * 4;
    for (int e = quad0; e < NE; e += stride) {
        int s = src[e], d = dst[e];
        float norm = dinv[s] * dinv[d];
        float v = h[(size_t)s * FH + lane] * norm;
        unsafeAtomicAdd(&agg[(size_t)d * FH + lane], v);
    }
}

// x1 = relu(agg + dinv^2*h + b1), in-place into agg; accumulate cluster sums
__global__ __launch_bounds__(256) void k_x1(const float* __restrict__ h,
                                            const float* __restrict__ dinv,
                                            const float* __restrict__ b1,
                                            const int* __restrict__ cid,
                                            float* __restrict__ agg,
                                            float* __restrict__ sums) {
    int g = blockIdx.x * 256 + threadIdx.x;
    int i = g >> 6, c = g & 63;
    if (i >= NN) return;
    float di = dinv[i];
    float v = agg[(size_t)i * FH + c] + di * di * h[(size_t)i * FH + c] + b1[c];
    v = fmaxf(v, 0.f);
    agg[(size_t)i * FH + c] = v;
    unsafeAtomicAdd(&sums[(size_t)cid[i] * FH + c], v);
}

// x_p = sums/counts; g[s] = dinv_p[s] * (x_p[s] @ W2)
__global__ __launch_bounds__(64) void k_pool(const float* __restrict__ sums,
                                             const int* __restrict__ counts,
                                             const float* __restrict__ W2,
                                             const float* __restrict__ dinvp,
                                             float* __restrict__ g) {
    __shared__ float xp[FH];
    int s = blockIdx.x, f = threadIdx.x;
    float cnt = fmaxf((float)counts[s], 1.0f);
    xp[f] = sums[(size_t)s * FH + f] / cnt;
    __syncthreads();
    float acc = 0.f;
    for (int j = 0; j < FH; ++j) acc = fmaf(xp[j], W2[j * FH + f], acc);
    g[(size_t)s * FH + f] = dinvp[s] * acc;
}

// x_p2[t] = dinv_p[t] * (g[t] + sum_{s: A_T[t][s]=1} g[s]) + b2
__global__ __launch_bounds__(64) void k_xp2(const float* __restrict__ AT,
                                            const float* __restrict__ g,
                                            const float* __restrict__ dinvp,
                                            const float* __restrict__ b2,
                                            float* __restrict__ xp2) {
    int t = blockIdx.x, lane = threadIdx.x;
    float acc = g[(size_t)t * FH + lane];  // self-loop term
    const float* row = AT + (size_t)t * KC;
    for (int sb = 0; sb < KC; sb += 64) {
        float a = row[sb + lane];
        unsigned long long m = __ballot(a != 0.f);
        while (m) {
            int j = __builtin_ctzll(m);
            m &= m - 1;
            acc += g[(size_t)(sb + j) * FH + lane];
        }
    }
    xp2[(size_t)t * FH + lane] = dinvp[t] * acc + b2[lane];
}

// out = xp2[cid] + relu(alpha) * (x1 @ W_skip + b_skip)
__global__ __launch_bounds__(256) void k_final(const float* __restrict__ x1,
                                               const float* __restrict__ Wsk,
                                               const float* __restrict__ bsk,
                                               const float* __restrict__ xp2,
                                               const int* __restrict__ cid,
                                               const float* __restrict__ alpha,
                                               float* __restrict__ out) {
    __shared__ float Ws[FH * FOUT];  // 16 KB
    int t = threadIdx.x;
    {
        const float4* wv = (const float4*)Wsk;
        float4* sv = (float4*)Ws;
        for (int i = t; i < FH * FOUT / 4; i += 256) sv[i] = wv[i];
    }
    __syncthreads();
    float a = fmaxf(alpha[0], 0.f);
    int col = t & 63, rq = t >> 6;
    int row0 = blockIdx.x * 16 + rq * 4;
    float acc0 = 0.f, acc1 = 0.f, acc2 = 0.f, acc3 = 0.f;
    const float4* x4 = (const float4*)x1;
    const int L = FH / 4;
    for (int k4 = 0; k4 < L; ++k4) {
        float4 a0 = x4[(size_t)(row0 + 0) * L + k4];
        float4 a1 = x4[(size_t)(row0 + 1) * L + k4];
        float4 a2 = x4[(size_t)(row0 + 2) * L + k4];
        float4 a3 = x4[(size_t)(row0 + 3) * L + k4];
        const float* wp = &Ws[k4 * 4 * FOUT + col];
        float w0 = wp[0], w1 = wp[FOUT], w2 = wp[2 * FOUT], w3 = wp[3 * FOUT];
        acc0 = fmaf(a0.x, w0, fmaf(a0.y, w1, fmaf(a0.z, w2, fmaf(a0.w, w3, acc0))));
        acc1 = fmaf(a1.x, w0, fmaf(a1.y, w1, fmaf(a1.z, w2, fmaf(a1.w, w3, acc1))));
        acc2 = fmaf(a2.x, w0, fmaf(a2.y, w1, fmaf(a2.z, w2, fmaf(a2.w, w3, acc2))));
        acc3 = fmaf(a3.x, w0, fmaf(a3.y, w1, fmaf(a3.z, w2, fmaf(a3.w, w3, acc3))));
    }
    int c0 = cid[row0 + 0], c1 = cid[row0 + 1], c2 = cid[row0 + 2], c3 = cid[row0 + 3];
    float bb = bsk[col];
    out[(size_t)(row0 + 0) * FOUT + col] = xp2[(size_t)c0 * FOUT + col] + a * (acc0 + bb);
    out[(size_t)(row0 + 1) * FOUT + col] = xp2[(size_t)c1 * FOUT + col] + a * (acc1 + bb);
    out[(size_t)(row0 + 2) * FOUT + col] = xp2[(size_t)c2 * FOUT + col] + a * (acc2 + bb);
    out[(size_t)(row0 + 3) * FOUT + col] = xp2[(size_t)c3 * FOUT + col] + a * (acc3 + bb);
}

extern "C" void kernel_launch(void* const* d_in, const int* in_sizes, int n_in,
                              void* d_out, int out_size, void* d_ws, size_t ws_size,
                              hipStream_t stream) {
    const float* x    = (const float*)d_in[0];
    const int*   ei   = (const int*)d_in[1];
    const int*   cid  = (const int*)d_in[2];
    const float* W1   = (const float*)d_in[3];
    const float* b1   = (const float*)d_in[4];
    const float* W2   = (const float*)d_in[5];
    const float* b2   = (const float*)d_in[6];
    const float* Wsk  = (const float*)d_in[7];
    const float* bsk  = (const float*)d_in[8];
    const float* alpha= (const float*)d_in[9];
    float* out = (float*)d_out;
    const int* src = ei;
    const int* dst = ei + NE;

    // workspace layout: zero-init region first (one memset covers it)
    char* ws = (char*)d_ws;
    size_t cur = 0;
    auto alloc = [&](size_t nb) { cur = (cur + 255) & ~(size_t)255; size_t o = cur; cur += nb; return o; };
    size_t o_agg  = alloc((size_t)NN * FH * 4);  // agg, becomes x1 in place
    size_t o_sums = alloc((size_t)KC * FH * 4);
    size_t o_AT   = alloc((size_t)KC * KC * 4);
    size_t o_deg  = alloc((size_t)NN * 4);
    size_t o_cnt  = alloc((size_t)KC * 4);
    size_t zero_bytes = cur;
    size_t o_h    = alloc((size_t)NN * FH * 4);
    size_t o_dinv = alloc((size_t)NN * 4);
    size_t o_g    = alloc((size_t)KC * FH * 4);
    size_t o_xp2  = alloc((size_t)KC * FH * 4);
    size_t o_dinvp= alloc((size_t)KC * 4);
    (void)ws_size; (void)in_sizes; (void)n_in; (void)out_size;

    float* agg  = (float*)(ws + o_agg);
    float* sums = (float*)(ws + o_sums);
    float* AT   = (float*)(ws + o_AT);
    int*   deg  = (int*)(ws + o_deg);
    int*   cnt  = (int*)(ws + o_cnt);
    float* h    = (float*)(ws + o_h);
    float* dinv = (float*)(ws + o_dinv);
    float* g    = (float*)(ws + o_g);
    float* xp2  = (float*)(ws + o_xp2);
    float* dinvp= (float*)(ws + o_dinvp);

    hipMemsetAsync(d_ws, 0, zero_bytes, stream);

    k_edge   <<<(NE + 255) / 256, 256, 0, stream>>>(src, dst, cid, deg, AT);
    k_degp   <<<KC, 64, 0, stream>>>(AT, dinvp);
    k_node   <<<(NN + 255) / 256, 256, 0, stream>>>(deg, cid, dinv, cnt);
    k_gemm1  <<<NN / 16, 256, 0, stream>>>(x, W1, h);
    k_scatter<<<8192, 256, 0, stream>>>(src, dst, dinv, h, agg);
    k_x1     <<<NN * FH / 256, 256, 0, stream>>>(h, dinv, b1, cid, agg, sums);
    k_pool   <<<KC, 64, 0, stream>>>(sums, cnt, W2, dinvp, g);
    k_xp2    <<<KC, 64, 0, stream>>>(AT, g, dinvp, b2, xp2);
    k_final  <<<NN / 16, 256, 0, stream>>>(agg, Wsk, bsk, xp2, cid, alpha, out);
}

// Round 2
// 475.374 us; speedup vs baseline: 1.0682x; 1.0682x over previous
//
#include <hip/hip_runtime.h>

#define NN 50000
#define NE 800000
#define FIN 128
#define FH 64
#define FOUT 64
#define KC 1024

// ---------------------------------------------------------------------------
// Edge pass: in-degree histogram + pooled adjacency (stored TRANSPOSED:
// A_T[cv][cu] = A[cu][cv], so later column-ops over A become row-ops).
// ---------------------------------------------------------------------------
__global__ __launch_bounds__(256) void k_edge(const int* __restrict__ src,
                                              const int* __restrict__ dst,
                                              const int* __restrict__ cid,
                                              int* __restrict__ deg,
                                              float* __restrict__ AT) {
    int e = blockIdx.x * 256 + threadIdx.x;
    if (e >= NE) return;
    int s = src[e], d = dst[e];
    atomicAdd(&deg[d], 1);
    int cu = cid[s], cv = cid[d];
    if (cu != cv) AT[cv * KC + cu] = 1.0f;  // racing same-value stores: benign
}

// deg_p[t] = 1 + sum_s A[s][t] = 1 + rowsum(A_T[t]); dinv_p = rsqrt
__global__ __launch_bounds__(64) void k_degp(const float* __restrict__ AT,
                                             float* __restrict__ dinvp) {
    int t = blockIdx.x, lane = threadIdx.x;
    const float* row = AT + (size_t)t * KC;
    float s = 0.f;
    for (int i = lane; i < KC; i += 64) s += row[i];
    for (int o = 32; o; o >>= 1) s += __shfl_down(s, o);
    if (lane == 0) dinvp[t] = rsqrtf(1.0f + s);
}

// per-node: dinv = rsqrt(deg+1); cluster counts
__global__ __launch_bounds__(256) void k_node(const int* __restrict__ deg,
                                              const int* __restrict__ cid,
                                              float* __restrict__ dinv,
                                              int* __restrict__ counts) {
    int i = blockIdx.x * 256 + threadIdx.x;
    if (i >= NN) return;
    dinv[i] = rsqrtf((float)deg[i] + 1.0f);
    atomicAdd(&counts[cid[i]], 1);
}

// Exclusive prefix scan of deg[0..NN) -> rowptr[0..NN]; deg becomes the fill
// cursor (deg[i] = rowptr[i] on exit).  Single block, 1024 threads, two
// passes over each thread's contiguous chunk (no big register array).
#define CHUNK 49  // 1024*49 = 50176 >= NN
__global__ __launch_bounds__(1024) void k_scan(int* __restrict__ deg,
                                               int* __restrict__ rowptr) {
    __shared__ int part[1024];
    int t = threadIdx.x;
    int lo = t * CHUNK, hi = min(lo + CHUNK, NN);
    int sum = 0;
    for (int i = lo; i < hi; ++i) sum += deg[i];
    part[t] = sum;
    __syncthreads();
    for (int off = 1; off < 1024; off <<= 1) {
        int v = (t >= off) ? part[t - off] : 0;
        __syncthreads();
        part[t] += v;
        __syncthreads();
    }
    int r = (t == 0) ? 0 : part[t - 1];
    for (int i = lo; i < hi; ++i) {
        int dv = deg[i];
        rowptr[i] = r;
        deg[i] = r;  // cursor for k_fill
        r += dv;
    }
    if (t == 1023) rowptr[NN] = part[1023];
}

// Bucket-fill CSR column (source-id) list. cursor==deg (holds rowptr copies).
__global__ __launch_bounds__(256) void k_fill(const int* __restrict__ src,
                                              const int* __restrict__ dst,
                                              int* __restrict__ cursor,
                                              int* __restrict__ col) {
    int e = blockIdx.x * 256 + threadIdx.x;
    if (e >= NE) return;
    int pos = atomicAdd(&cursor[dst[e]], 1);
    col[pos] = src[e];
}

// h = x @ W1.  Block = 256 thr = 4 row-quads x 64 cols; 16 rows/block,
// 4 rows/thread so each LDS W1 read feeds 4 FMAs.
__global__ __launch_bounds__(256) void k_gemm1(const float* __restrict__ x,
                                               const float* __restrict__ W1,
                                               float* __restrict__ h) {
    __shared__ float W1s[FIN * FH];  // 32 KB
    int t = threadIdx.x;
    {
        const float4* wv = (const float4*)W1;
        float4* sv = (float4*)W1s;
        for (int i = t; i < FIN * FH / 4; i += 256) sv[i] = wv[i];
    }
    __syncthreads();
    int col = t & 63, rq = t >> 6;
    int row0 = blockIdx.x * 16 + rq * 4;
    float acc0 = 0.f, acc1 = 0.f, acc2 = 0.f, acc3 = 0.f;
    const float4* x4 = (const float4*)x;
    const int L = FIN / 4;
    for (int k4 = 0; k4 < L; ++k4) {
        float4 a0 = x4[(size_t)(row0 + 0) * L + k4];
        float4 a1 = x4[(size_t)(row0 + 1) * L + k4];
        float4 a2 = x4[(size_t)(row0 + 2) * L + k4];
        float4 a3 = x4[(size_t)(row0 + 3) * L + k4];
        const float* wp = &W1s[k4 * 4 * FH + col];
        float w0 = wp[0], w1 = wp[FH], w2 = wp[2 * FH], w3 = wp[3 * FH];
        acc0 = fmaf(a0.x, w0, fmaf(a0.y, w1, fmaf(a0.z, w2, fmaf(a0.w, w3, acc0))));
        acc1 = fmaf(a1.x, w0, fmaf(a1.y, w1, fmaf(a1.z, w2, fmaf(a1.w, w3, acc1))));
        acc2 = fmaf(a2.x, w0, fmaf(a2.y, w1, fmaf(a2.z, w2, fmaf(a2.w, w3, acc2))));
        acc3 = fmaf(a3.x, w0, fmaf(a3.y, w1, fmaf(a3.z, w2, fmaf(a3.w, w3, acc3))));
    }
    h[(size_t)(row0 + 0) * FH + col] = acc0;
    h[(size_t)(row0 + 1) * FH + col] = acc1;
    h[(size_t)(row0 + 2) * FH + col] = acc2;
    h[(size_t)(row0 + 3) * FH + col] = acc3;
}

// Gather form of the edge aggregation + fused x1 epilogue:
// x1[d] = relu(dinv[d]*sum_{s in N(d)} dinv[s]*h[s] + dinv[d]^2*h[d] + b1)
// then cluster-sum atomics.  One wave per dst node, lane = channel.
__global__ __launch_bounds__(256) void k_gather(const int* __restrict__ rowptr,
                                                const int* __restrict__ col,
                                                const float* __restrict__ dinv,
                                                const float* __restrict__ h,
                                                const float* __restrict__ b1,
                                                const int* __restrict__ cid,
                                                float* __restrict__ x1,
                                                float* __restrict__ sums) {
    int lane = threadIdx.x & 63;
    int node = blockIdx.x * 4 + (threadIdx.x >> 6);
    if (node >= NN) return;
    int rp = rowptr[node], re = rowptr[node + 1];
    float acc = 0.f;
    for (int base = rp; base < re; base += 64) {
        int cnt = min(64, re - base);
        int s = (lane < cnt) ? col[base + lane] : 0;
        float w = (lane < cnt) ? dinv[s] : 0.f;
        for (int j = 0; j < cnt; ++j) {
            int ss = __shfl(s, j);
            float ww = __shfl(w, j);
            acc = fmaf(ww, h[(size_t)ss * FH + lane], acc);
        }
    }
    float di = dinv[node];
    float v = di * acc + di * di * h[(size_t)node * FH + lane] + b1[lane];
    v = fmaxf(v, 0.f);
    x1[(size_t)node * FH + lane] = v;
    unsafeAtomicAdd(&sums[(size_t)cid[node] * FH + lane], v);
}

// x_p = sums/counts; g[s] = dinv_p[s] * (x_p[s] @ W2)
__global__ __launch_bounds__(64) void k_pool(const float* __restrict__ sums,
                                             const int* __restrict__ counts,
                                             const float* __restrict__ W2,
                                             const float* __restrict__ dinvp,
                                             float* __restrict__ g) {
    __shared__ float xp[FH];
    int s = blockIdx.x, f = threadIdx.x;
    float cnt = fmaxf((float)counts[s], 1.0f);
    xp[f] = sums[(size_t)s * FH + f] / cnt;
    __syncthreads();
    float acc = 0.f;
    for (int j = 0; j < FH; ++j) acc = fmaf(xp[j], W2[j * FH + f], acc);
    g[(size_t)s * FH + f] = dinvp[s] * acc;
}

// Dense pooled aggregation: xp2[t] = dinvp[t]*(g[t] + sum_s AT[t,s]*g[s]) + b2
// One wave per target row; broadcast-FMA over the 55%-dense AT row.
__global__ __launch_bounds__(256) void k_xp2(const float* __restrict__ AT,
                                             const float* __restrict__ g,
                                             const float* __restrict__ dinvp,
                                             const float* __restrict__ b2,
                                             float* __restrict__ xp2) {
    int lane = threadIdx.x & 63;
    int t = blockIdx.x * 4 + (threadIdx.x >> 6);
    float acc = g[(size_t)t * FH + lane];  // self-loop
    const float* row = AT + (size_t)t * KC;
    for (int sb = 0; sb < KC; sb += 64) {
        float a = row[sb + lane];
        for (int j = 0; j < 64; ++j) {
            float aj = __shfl(a, j);
            acc = fmaf(aj, g[(size_t)(sb + j) * FH + lane], acc);
        }
    }
    xp2[(size_t)t * FH + lane] = dinvp[t] * acc + b2[lane];
}

// out = xp2[cid] + relu(alpha) * (x1 @ W_skip + b_skip)
__global__ __launch_bounds__(256) void k_final(const float* __restrict__ x1,
                                               const float* __restrict__ Wsk,
                                               const float* __restrict__ bsk,
                                               const float* __restrict__ xp2,
                                               const int* __restrict__ cid,
                                               const float* __restrict__ alpha,
                                               float* __restrict__ out) {
    __shared__ float Ws[FH * FOUT];  // 16 KB
    int t = threadIdx.x;
    {
        const float4* wv = (const float4*)Wsk;
        float4* sv = (float4*)Ws;
        for (int i = t; i < FH * FOUT / 4; i += 256) sv[i] = wv[i];
    }
    __syncthreads();
    float a = fmaxf(alpha[0], 0.f);
    int col = t & 63, rq = t >> 6;
    int row0 = blockIdx.x * 16 + rq * 4;
    float acc0 = 0.f, acc1 = 0.f, acc2 = 0.f, acc3 = 0.f;
    const float4* x4 = (const float4*)x1;
    const int L = FH / 4;
    for (int k4 = 0; k4 < L; ++k4) {
        float4 a0 = x4[(size_t)(row0 + 0) * L + k4];
        float4 a1 = x4[(size_t)(row0 + 1) * L + k4];
        float4 a2 = x4[(size_t)(row0 + 2) * L + k4];
        float4 a3 = x4[(size_t)(row0 + 3) * L + k4];
        const float* wp = &Ws[k4 * 4 * FOUT + col];
        float w0 = wp[0], w1 = wp[FOUT], w2 = wp[2 * FOUT], w3 = wp[3 * FOUT];
        acc0 = fmaf(a0.x, w0, fmaf(a0.y, w1, fmaf(a0.z, w2, fmaf(a0.w, w3, acc0))));
        acc1 = fmaf(a1.x, w0, fmaf(a1.y, w1, fmaf(a1.z, w2, fmaf(a1.w, w3, acc1))));
        acc2 = fmaf(a2.x, w0, fmaf(a2.y, w1, fmaf(a2.z, w2, fmaf(a2.w, w3, acc2))));
        acc3 = fmaf(a3.x, w0, fmaf(a3.y, w1, fmaf(a3.z, w2, fmaf(a3.w, w3, acc3))));
    }
    int c0 = cid[row0 + 0], c1 = cid[row0 + 1], c2 = cid[row0 + 2], c3 = cid[row0 + 3];
    float bb = bsk[col];
    out[(size_t)(row0 + 0) * FOUT + col] = xp2[(size_t)c0 * FOUT + col] + a * (acc0 + bb);
    out[(size_t)(row0 + 1) * FOUT + col] = xp2[(size_t)c1 * FOUT + col] + a * (acc1 + bb);
    out[(size_t)(row0 + 2) * FOUT + col] = xp2[(size_t)c2 * FOUT + col] + a * (acc2 + bb);
    out[(size_t)(row0 + 3) * FOUT + col] = xp2[(size_t)c3 * FOUT + col] + a * (acc3 + bb);
}

extern "C" void kernel_launch(void* const* d_in, const int* in_sizes, int n_in,
                              void* d_out, int out_size, void* d_ws, size_t ws_size,
                              hipStream_t stream) {
    const float* x    = (const float*)d_in[0];
    const int*   ei   = (const int*)d_in[1];
    const int*   cid  = (const int*)d_in[2];
    const float* W1   = (const float*)d_in[3];
    const float* b1   = (const float*)d_in[4];
    const float* W2   = (const float*)d_in[5];
    const float* b2   = (const float*)d_in[6];
    const float* Wsk  = (const float*)d_in[7];
    const float* bsk  = (const float*)d_in[8];
    const float* alpha= (const float*)d_in[9];
    float* out = (float*)d_out;
    const int* src = ei;
    const int* dst = ei + NE;

    // workspace layout: zero-init region first (one memset covers it)
    char* ws = (char*)d_ws;
    size_t cur = 0;
    auto alloc = [&](size_t nb) { cur = (cur + 255) & ~(size_t)255; size_t o = cur; cur += nb; return o; };
    size_t o_sums = alloc((size_t)KC * FH * 4);
    size_t o_AT   = alloc((size_t)KC * KC * 4);
    size_t o_deg  = alloc((size_t)NN * 4);      // becomes CSR cursor after scan
    size_t o_cnt  = alloc((size_t)KC * 4);
    size_t zero_bytes = cur;
    size_t o_x1   = alloc((size_t)NN * FH * 4);
    size_t o_h    = alloc((size_t)NN * FH * 4);
    size_t o_rp   = alloc((size_t)(NN + 1) * 4);
    size_t o_col  = alloc((size_t)NE * 4);
    size_t o_dinv = alloc((size_t)NN * 4);
    size_t o_g    = alloc((size_t)KC * FH * 4);
    size_t o_xp2  = alloc((size_t)KC * FH * 4);
    size_t o_dinvp= alloc((size_t)KC * 4);
    (void)ws_size; (void)in_sizes; (void)n_in; (void)out_size;

    float* sums = (float*)(ws + o_sums);
    float* AT   = (float*)(ws + o_AT);
    int*   deg  = (int*)(ws + o_deg);
    int*   cnt  = (int*)(ws + o_cnt);
    float* x1   = (float*)(ws + o_x1);
    float* h    = (float*)(ws + o_h);
    int*   rp   = (int*)(ws + o_rp);
    int*   colb = (int*)(ws + o_col);
    float* dinv = (float*)(ws + o_dinv);
    float* g    = (float*)(ws + o_g);
    float* xp2  = (float*)(ws + o_xp2);
    float* dinvp= (float*)(ws + o_dinvp);

    hipMemsetAsync(d_ws, 0, zero_bytes, stream);

    k_edge  <<<(NE + 255) / 256, 256, 0, stream>>>(src, dst, cid, deg, AT);
    k_degp  <<<KC, 64, 0, stream>>>(AT, dinvp);
    k_node  <<<(NN + 255) / 256, 256, 0, stream>>>(deg, cid, dinv, cnt);
    k_scan  <<<1, 1024, 0, stream>>>(deg, rp);
    k_fill  <<<(NE + 255) / 256, 256, 0, stream>>>(src, dst, deg, colb);
    k_gemm1 <<<NN / 16, 256, 0, stream>>>(x, W1, h);
    k_gather<<<(NN + 3) / 4, 256, 0, stream>>>(rp, colb, dinv, h, b1, cid, x1, sums);
    k_pool  <<<KC, 64, 0, stream>>>(sums, cnt, W2, dinvp, g);
    k_xp2   <<<KC / 4, 256, 0, stream>>>(AT, g, dinvp, b2, xp2);
    k_final <<<NN / 16, 256, 0, stream>>>(x1, Wsk, bsk, xp2, cid, alpha, out);
}

// Round 3
// 376.877 us; speedup vs baseline: 1.3474x; 1.2613x over previous
//
#include <hip/hip_runtime.h>

#define NN 50000
#define NE 800000
#define FIN 128
#define FH 64
#define FOUT 64
#define KC 1024
#define NB1 ((NN + 255) / 256)  // 196 chunks for the scan hierarchy

// ---------------------------------------------------------------------------
// Edge pass: in-degree histogram + pooled adjacency (stored TRANSPOSED:
// A_T[cv][cu] = A[cu][cv], so later column-ops over A become row-ops).
// ---------------------------------------------------------------------------
__global__ __launch_bounds__(256) void k_edge(const int* __restrict__ src,
                                              const int* __restrict__ dst,
                                              const int* __restrict__ cid,
                                              int* __restrict__ deg,
                                              float* __restrict__ AT) {
    int e = blockIdx.x * 256 + threadIdx.x;
    if (e >= NE) return;
    int s = src[e], d = dst[e];
    atomicAdd(&deg[d], 1);
    int cu = cid[s], cv = cid[d];
    if (cu != cv) AT[cv * KC + cu] = 1.0f;  // racing same-value stores: benign
}

// deg_p[t] = 1 + sum_s A[s][t] = 1 + rowsum(A_T[t]); dinv_p = rsqrt
__global__ __launch_bounds__(64) void k_degp(const float* __restrict__ AT,
                                             float* __restrict__ dinvp) {
    int t = blockIdx.x, lane = threadIdx.x;
    const float* row = AT + (size_t)t * KC;
    float s = 0.f;
    for (int i = lane; i < KC; i += 64) s += row[i];
    for (int o = 32; o; o >>= 1) s += __shfl_down(s, o);
    if (lane == 0) dinvp[t] = rsqrtf(1.0f + s);
}

// per-node: dinv = rsqrt(deg+1); cluster counts
__global__ __launch_bounds__(256) void k_node(const int* __restrict__ deg,
                                              const int* __restrict__ cid,
                                              float* __restrict__ dinv,
                                              int* __restrict__ counts) {
    int i = blockIdx.x * 256 + threadIdx.x;
    if (i >= NN) return;
    dinv[i] = rsqrtf((float)deg[i] + 1.0f);
    atomicAdd(&counts[cid[i]], 1);
}

// --- reduce-then-scan hierarchy (replaces the 111us serial 1-block scan) ---
// pass 1: per-256-chunk sums of deg -> partials[NB1]
__global__ __launch_bounds__(256) void k_scan1(const int* __restrict__ deg,
                                               int* __restrict__ partials) {
    __shared__ int ws[4];
    int i = blockIdx.x * 256 + threadIdx.x;
    int v = (i < NN) ? deg[i] : 0;
    for (int o = 32; o; o >>= 1) v += __shfl_down(v, o);
    int lane = threadIdx.x & 63, w = threadIdx.x >> 6;
    if (lane == 0) ws[w] = v;
    __syncthreads();
    if (threadIdx.x == 0)
        partials[blockIdx.x] = ws[0] + ws[1] + ws[2] + ws[3];
}

// pass 2: one block exclusive-scans partials[NB1] in place; rowptr[NN]=total
__global__ __launch_bounds__(256) void k_scan2(int* __restrict__ partials,
                                               int* __restrict__ rowptr) {
    __shared__ int sm[256];
    int t = threadIdx.x;
    int v = (t < NB1) ? partials[t] : 0;
    sm[t] = v;
    __syncthreads();
    for (int off = 1; off < 256; off <<= 1) {
        int u = (t >= off) ? sm[t - off] : 0;
        __syncthreads();
        sm[t] += u;
        __syncthreads();
    }
    if (t < NB1) partials[t] = sm[t] - v;  // exclusive
    if (t == 255) rowptr[NN] = sm[255];
}

// pass 3: local exclusive scan + block offset -> rowptr & cursor(deg)
__global__ __launch_bounds__(256) void k_scan3(int* __restrict__ deg,
                                               const int* __restrict__ partials,
                                               int* __restrict__ rowptr) {
    __shared__ int sm[256];
    int t = threadIdx.x;
    int i = blockIdx.x * 256 + t;
    int v = (i < NN) ? deg[i] : 0;
    sm[t] = v;
    __syncthreads();
    for (int off = 1; off < 256; off <<= 1) {
        int u = (t >= off) ? sm[t - off] : 0;
        __syncthreads();
        sm[t] += u;
        __syncthreads();
    }
    if (i < NN) {
        int r = partials[blockIdx.x] + sm[t] - v;
        rowptr[i] = r;
        deg[i] = r;  // fill cursor
    }
}

// Bucket-fill CSR column (source-id) list. cursor==deg (holds rowptr copies).
__global__ __launch_bounds__(256) void k_fill(const int* __restrict__ src,
                                              const int* __restrict__ dst,
                                              int* __restrict__ cursor,
                                              int* __restrict__ col) {
    int e = blockIdx.x * 256 + threadIdx.x;
    if (e >= NE) return;
    int pos = atomicAdd(&cursor[dst[e]], 1);
    col[pos] = src[e];
}

// h = x @ W1.  Block = 256 thr = 4 row-quads x 64 cols; 16 rows/block,
// 4 rows/thread so each LDS W1 read feeds 4 FMAs.
__global__ __launch_bounds__(256) void k_gemm1(const float* __restrict__ x,
                                               const float* __restrict__ W1,
                                               float* __restrict__ h) {
    __shared__ float W1s[FIN * FH];  // 32 KB
    int t = threadIdx.x;
    {
        const float4* wv = (const float4*)W1;
        float4* sv = (float4*)W1s;
        for (int i = t; i < FIN * FH / 4; i += 256) sv[i] = wv[i];
    }
    __syncthreads();
    int col = t & 63, rq = t >> 6;
    int row0 = blockIdx.x * 16 + rq * 4;
    float acc0 = 0.f, acc1 = 0.f, acc2 = 0.f, acc3 = 0.f;
    const float4* x4 = (const float4*)x;
    const int L = FIN / 4;
    for (int k4 = 0; k4 < L; ++k4) {
        float4 a0 = x4[(size_t)(row0 + 0) * L + k4];
        float4 a1 = x4[(size_t)(row0 + 1) * L + k4];
        float4 a2 = x4[(size_t)(row0 + 2) * L + k4];
        float4 a3 = x4[(size_t)(row0 + 3) * L + k4];
        const float* wp = &W1s[k4 * 4 * FH + col];
        float w0 = wp[0], w1 = wp[FH], w2 = wp[2 * FH], w3 = wp[3 * FH];
        acc0 = fmaf(a0.x, w0, fmaf(a0.y, w1, fmaf(a0.z, w2, fmaf(a0.w, w3, acc0))));
        acc1 = fmaf(a1.x, w0, fmaf(a1.y, w1, fmaf(a1.z, w2, fmaf(a1.w, w3, acc1))));
        acc2 = fmaf(a2.x, w0, fmaf(a2.y, w1, fmaf(a2.z, w2, fmaf(a2.w, w3, acc2))));
        acc3 = fmaf(a3.x, w0, fmaf(a3.y, w1, fmaf(a3.z, w2, fmaf(a3.w, w3, acc3))));
    }
    h[(size_t)(row0 + 0) * FH + col] = acc0;
    h[(size_t)(row0 + 1) * FH + col] = acc1;
    h[(size_t)(row0 + 2) * FH + col] = acc2;
    h[(size_t)(row0 + 3) * FH + col] = acc3;
}

// Gather form of the edge aggregation + fused x1 epilogue:
// x1[d] = relu(dinv[d]*sum_{s in N(d)} dinv[s]*h[s] + dinv[d]^2*h[d] + b1)
// then cluster-sum atomics.  One wave per dst node, lane = channel.
__global__ __launch_bounds__(256) void k_gather(const int* __restrict__ rowptr,
                                                const int* __restrict__ col,
                                                const float* __restrict__ dinv,
                                                const float* __restrict__ h,
                                                const float* __restrict__ b1,
                                                const int* __restrict__ cid,
                                                float* __restrict__ x1,
                                                float* __restrict__ sums) {
    int lane = threadIdx.x & 63;
    int node = blockIdx.x * 4 + (threadIdx.x >> 6);
    if (node >= NN) return;
    int rp = rowptr[node], re = rowptr[node + 1];
    float acc = 0.f;
    for (int base = rp; base < re; base += 64) {
        int cnt = min(64, re - base);
        int s = (lane < cnt) ? col[base + lane] : 0;
        float w = (lane < cnt) ? dinv[s] : 0.f;
        for (int j = 0; j < cnt; ++j) {
            int ss = __shfl(s, j);
            float ww = __shfl(w, j);
            acc = fmaf(ww, h[(size_t)ss * FH + lane], acc);
        }
    }
    float di = dinv[node];
    float v = di * acc + di * di * h[(size_t)node * FH + lane] + b1[lane];
    v = fmaxf(v, 0.f);
    x1[(size_t)node * FH + lane] = v;
    unsafeAtomicAdd(&sums[(size_t)cid[node] * FH + lane], v);
}

// x_p = sums/counts; g[s] = dinv_p[s] * (x_p[s] @ W2)
__global__ __launch_bounds__(64) void k_pool(const float* __restrict__ sums,
                                             const int* __restrict__ counts,
                                             const float* __restrict__ W2,
                                             const float* __restrict__ dinvp,
                                             float* __restrict__ g) {
    __shared__ float xp[FH];
    int s = blockIdx.x, f = threadIdx.x;
    float cnt = fmaxf((float)counts[s], 1.0f);
    xp[f] = sums[(size_t)s * FH + f] / cnt;
    __syncthreads();
    float acc = 0.f;
    for (int j = 0; j < FH; ++j) acc = fmaf(xp[j], W2[j * FH + f], acc);
    g[(size_t)s * FH + f] = dinvp[s] * acc;
}

// Dense pooled aggregation: xp2[t] = dinvp[t]*(g[t] + sum_s AT[t,s]*g[s]) + b2
// One wave per target row; broadcast-FMA over the 55%-dense AT row.
__global__ __launch_bounds__(256) void k_xp2(const float* __restrict__ AT,
                                             const float* __restrict__ g,
                                             const float* __restrict__ dinvp,
                                             const float* __restrict__ b2,
                                             float* __restrict__ xp2) {
    int lane = threadIdx.x & 63;
    int t = blockIdx.x * 4 + (threadIdx.x >> 6);
    float acc = g[(size_t)t * FH + lane];  // self-loop
    const float* row = AT + (size_t)t * KC;
    for (int sb = 0; sb < KC; sb += 64) {
        float a = row[sb + lane];
        for (int j = 0; j < 64; ++j) {
            float aj = __shfl(a, j);
            acc = fmaf(aj, g[(size_t)(sb + j) * FH + lane], acc);
        }
    }
    xp2[(size_t)t * FH + lane] = dinvp[t] * acc + b2[lane];
}

// out = xp2[cid] + relu(alpha) * (x1 @ W_skip + b_skip)
__global__ __launch_bounds__(256) void k_final(const float* __restrict__ x1,
                                               const float* __restrict__ Wsk,
                                               const float* __restrict__ bsk,
                                               const float* __restrict__ xp2,
                                               const int* __restrict__ cid,
                                               const float* __restrict__ alpha,
                                               float* __restrict__ out) {
    __shared__ float Ws[FH * FOUT];  // 16 KB
    int t = threadIdx.x;
    {
        const float4* wv = (const float4*)Wsk;
        float4* sv = (float4*)Ws;
        for (int i = t; i < FH * FOUT / 4; i += 256) sv[i] = wv[i];
    }
    __syncthreads();
    float a = fmaxf(alpha[0], 0.f);
    int col = t & 63, rq = t >> 6;
    int row0 = blockIdx.x * 16 + rq * 4;
    float acc0 = 0.f, acc1 = 0.f, acc2 = 0.f, acc3 = 0.f;
    const float4* x4 = (const float4*)x1;
    const int L = FH / 4;
    for (int k4 = 0; k4 < L; ++k4) {
        float4 a0 = x4[(size_t)(row0 + 0) * L + k4];
        float4 a1 = x4[(size_t)(row0 + 1) * L + k4];
        float4 a2 = x4[(size_t)(row0 + 2) * L + k4];
        float4 a3 = x4[(size_t)(row0 + 3) * L + k4];
        const float* wp = &Ws[k4 * 4 * FOUT + col];
        float w0 = wp[0], w1 = wp[FOUT], w2 = wp[2 * FOUT], w3 = wp[3 * FOUT];
        acc0 = fmaf(a0.x, w0, fmaf(a0.y, w1, fmaf(a0.z, w2, fmaf(a0.w, w3, acc0))));
        acc1 = fmaf(a1.x, w0, fmaf(a1.y, w1, fmaf(a1.z, w2, fmaf(a1.w, w3, acc1))));
        acc2 = fmaf(a2.x, w0, fmaf(a2.y, w1, fmaf(a2.z, w2, fmaf(a2.w, w3, acc2))));
        acc3 = fmaf(a3.x, w0, fmaf(a3.y, w1, fmaf(a3.z, w2, fmaf(a3.w, w3, acc3))));
    }
    int c0 = cid[row0 + 0], c1 = cid[row0 + 1], c2 = cid[row0 + 2], c3 = cid[row0 + 3];
    float bb = bsk[col];
    out[(size_t)(row0 + 0) * FOUT + col] = xp2[(size_t)c0 * FOUT + col] + a * (acc0 + bb);
    out[(size_t)(row0 + 1) * FOUT + col] = xp2[(size_t)c1 * FOUT + col] + a * (acc1 + bb);
    out[(size_t)(row0 + 2) * FOUT + col] = xp2[(size_t)c2 * FOUT + col] + a * (acc2 + bb);
    out[(size_t)(row0 + 3) * FOUT + col] = xp2[(size_t)c3 * FOUT + col] + a * (acc3 + bb);
}

extern "C" void kernel_launch(void* const* d_in, const int* in_sizes, int n_in,
                              void* d_out, int out_size, void* d_ws, size_t ws_size,
                              hipStream_t stream) {
    const float* x    = (const float*)d_in[0];
    const int*   ei   = (const int*)d_in[1];
    const int*   cid  = (const int*)d_in[2];
    const float* W1   = (const float*)d_in[3];
    const float* b1   = (const float*)d_in[4];
    const float* W2   = (const float*)d_in[5];
    const float* b2   = (const float*)d_in[6];
    const float* Wsk  = (const float*)d_in[7];
    const float* bsk  = (const float*)d_in[8];
    const float* alpha= (const float*)d_in[9];
    float* out = (float*)d_out;
    const int* src = ei;
    const int* dst = ei + NE;

    // workspace layout: zero-init region first (one memset covers it)
    char* ws = (char*)d_ws;
    size_t cur = 0;
    auto alloc = [&](size_t nb) { cur = (cur + 255) & ~(size_t)255; size_t o = cur; cur += nb; return o; };
    size_t o_sums = alloc((size_t)KC * FH * 4);
    size_t o_AT   = alloc((size_t)KC * KC * 4);
    size_t o_deg  = alloc((size_t)NN * 4);      // becomes CSR cursor after scan
    size_t o_cnt  = alloc((size_t)KC * 4);
    size_t zero_bytes = cur;
    size_t o_x1   = alloc((size_t)NN * FH * 4);
    size_t o_h    = alloc((size_t)NN * FH * 4);
    size_t o_rp   = alloc((size_t)(NN + 1) * 4);
    size_t o_col  = alloc((size_t)NE * 4);
    size_t o_dinv = alloc((size_t)NN * 4);
    size_t o_g    = alloc((size_t)KC * FH * 4);
    size_t o_xp2  = alloc((size_t)KC * FH * 4);
    size_t o_dinvp= alloc((size_t)KC * 4);
    size_t o_part = alloc((size_t)NB1 * 4);
    (void)ws_size; (void)in_sizes; (void)n_in; (void)out_size;

    float* sums = (float*)(ws + o_sums);
    float* AT   = (float*)(ws + o_AT);
    int*   deg  = (int*)(ws + o_deg);
    int*   cnt  = (int*)(ws + o_cnt);
    float* x1   = (float*)(ws + o_x1);
    float* h    = (float*)(ws + o_h);
    int*   rp   = (int*)(ws + o_rp);
    int*   colb = (int*)(ws + o_col);
    float* dinv = (float*)(ws + o_dinv);
    float* g    = (float*)(ws + o_g);
    float* xp2  = (float*)(ws + o_xp2);
    float* dinvp= (float*)(ws + o_dinvp);
    int*   part = (int*)(ws + o_part);

    hipMemsetAsync(d_ws, 0, zero_bytes, stream);

    k_edge  <<<(NE + 255) / 256, 256, 0, stream>>>(src, dst, cid, deg, AT);
    k_degp  <<<KC, 64, 0, stream>>>(AT, dinvp);
    k_node  <<<(NN + 255) / 256, 256, 0, stream>>>(deg, cid, dinv, cnt);
    k_scan1 <<<NB1, 256, 0, stream>>>(deg, part);
    k_scan2 <<<1, 256, 0, stream>>>(part, rp);
    k_scan3 <<<NB1, 256, 0, stream>>>(deg, part, rp);
    k_fill  <<<(NE + 255) / 256, 256, 0, stream>>>(src, dst, deg, colb);
    k_gemm1 <<<NN / 16, 256, 0, stream>>>(x, W1, h);
    k_gather<<<(NN + 3) / 4, 256, 0, stream>>>(rp, colb, dinv, h, b1, cid, x1, sums);
    k_pool  <<<KC, 64, 0, stream>>>(sums, cnt, W2, dinvp, g);
    k_xp2   <<<KC / 4, 256, 0, stream>>>(AT, g, dinvp, b2, xp2);
    k_final <<<NN / 16, 256, 0, stream>>>(x1, Wsk, bsk, xp2, cid, alpha, out);
}